// Round 4
// baseline (178.222 us; speedup 1.0000x reference)
//
#include <hip/hip_runtime.h>
#include <math.h>

// FFTConvReservoir: y = tanh(ifft(fft(u)*fft(K)).real + D*u); B=8,H=256,L=8192 fp32.
// Round 4: single fused kernel.
//  - Each block computes FFT(K[h]) itself (passes A,B,C) keeping the spectrum in the
//    pass-C register layout — exactly the operand layout the merged multiply needs.
//    No Kf workspace, no second kernel. Blocks sharing h are {h,h+256,h+512,h+768},
//    all congruent mod 8 -> same XCD -> K row fetched from HBM once.
//  - Skip + normalization folded into the spectrum: kw = (FFT(K)+D)/N, so the
//    epilogue is just tanh(reg) — u is read exactly once.
//  - LDS XOR swizzle keeps every pass pattern <=2-way (free, verified round 3: 0 conflicts).

#define LL 8192
#define NT 256
#define HH 256
#define TWO_PI 6.2831853071795864f
#define CP16 0.98078528040323f   // cos(pi/16)
#define SP16 0.19509032201613f   // sin(pi/16)
#define CP8  0.92387953251129f   // cos(pi/8)
#define SP8  0.38268343236509f   // sin(pi/8)

__device__ __forceinline__ int PHYS(int i) {
    return i ^ ((i >> 5) & 15) ^ (((i >> 8) & 1) << 4);
}
__device__ __forceinline__ float fast_tanh(float x) {
    float e = __expf(2.0f * x);
    return 1.0f - 2.0f / (e + 1.0f);
}

// Twiddle pyramid: level j at offset (1<<j)-1, length 2^j.
template<int JT>
__device__ __forceinline__ void fill_pyr_cs(float c0, float s0, float Er, float Ei,
                                            float* twr, float* twi) {
    const int off = (1 << JT) - 1;
    twr[off] = c0; twi[off] = s0;
    #pragma unroll
    for (int m = 1; m < (1 << JT); ++m) {
        const float pr = twr[off + m - 1], pi = twi[off + m - 1];
        twr[off + m] = pr * Er - pi * Ei;
        twi[off + m] = pr * Ei + pi * Er;
    }
    #pragma unroll
    for (int j = JT - 1; j >= 0; --j) {
        #pragma unroll
        for (int m = 0; m < (1 << j); ++m) {
            const float a = twr[(2 << j) - 1 + m], b = twi[(2 << j) - 1 + m];
            twr[(1 << j) - 1 + m] = a * a - b * b;
            twi[(1 << j) - 1 + m] = 2.0f * a * b;
        }
    }
}
template<int JT>
__device__ __forceinline__ void fill_pyr(float ang0, float Er, float Ei,
                                         float* twr, float* twi) {
    float s, c;
    __sincosf(ang0, &s, &c);
    fill_pyr_cs<JT>(c, s, Er, Ei, twr, twi);
}

template<int R2>
__device__ __forceinline__ void dif_apply(float* xr, float* xi,
                                          const float* twr, const float* twi) {
    #pragma unroll
    for (int j = R2 - 1; j >= 0; --j) {
        #pragma unroll
        for (int q = 0; q < (1 << (R2 - 1)); ++q) {
            const int mm = q & ((1 << j) - 1);
            const int m0 = ((q >> j) << (j + 1)) | mm;
            const int m1 = m0 + (1 << j);
            const float wr = twr[(1 << j) - 1 + mm], wi = twi[(1 << j) - 1 + mm];
            const float ar = xr[m0], ai = xi[m0], br = xr[m1], bi = xi[m1];
            xr[m0] = ar + br; xi[m0] = ai + bi;
            const float dr = ar - br, di = ai - bi;
            xr[m1] = dr * wr - di * wi;
            xi[m1] = dr * wi + di * wr;
        }
    }
}
template<int R2>
__device__ __forceinline__ void dit_apply(float* xr, float* xi,
                                          const float* twr, const float* twi) {
    #pragma unroll
    for (int j = 0; j < R2; ++j) {
        #pragma unroll
        for (int q = 0; q < (1 << (R2 - 1)); ++q) {
            const int mm = q & ((1 << j) - 1);
            const int m0 = ((q >> j) << (j + 1)) | mm;
            const int m1 = m0 + (1 << j);
            const float wr = twr[(1 << j) - 1 + mm], wi = twi[(1 << j) - 1 + mm];
            const float br = xr[m1] * wr - xi[m1] * wi;
            const float bi = xr[m1] * wi + xi[m1] * wr;
            const float ar = xr[m0], ai = xi[m0];
            xr[m0] = ar + br; xi[m0] = ai + bi;
            xr[m1] = ar - br; xi[m1] = ai - bi;
        }
    }
}

// Fwd pass A (stages 12..8): xr/xi = natural elements [tid + 256m]; writes LDS.
__device__ __forceinline__ void fwd_A(float* xr, float* xi, int tid,
                                      float* re, float* im) {
    float twr[31], twi[31];
    fill_pyr<4>(-(TWO_PI / 8192.0f) * (float)tid, CP16, -SP16, twr, twi);
    dif_apply<5>(xr, xi, twr, twi);
    #pragma unroll
    for (int m = 0; m < 32; ++m) {
        const int p = PHYS(tid + (m << 8));
        re[p] = xr[m]; im[p] = xi[m];
    }
}
// Fwd pass B (stages 7..4).
__device__ __forceinline__ void fwd_B(int tid, float* re, float* im) {
    #pragma unroll
    for (int gg = 0; gg < 2; ++gg) {
        const int g = tid + (gg << 8);
        const int base = ((g >> 4) << 8) | (g & 15);
        float xr[16], xi[16], twr[15], twi[15];
        #pragma unroll
        for (int m = 0; m < 16; ++m) {
            const int p = PHYS(base + (m << 4));
            xr[m] = re[p]; xi[m] = im[p];
        }
        fill_pyr<3>(-(TWO_PI / 256.0f) * (float)(g & 15), CP8, -SP8, twr, twi);
        dif_apply<4>(xr, xi, twr, twi);
        #pragma unroll
        for (int m = 0; m < 16; ++m) {
            const int p = PHYS(base + (m << 4));
            re[p] = xr[m]; im[p] = xi[m];
        }
    }
}
// Inv pass B' (stages 4..7, conjugate twiddles).
__device__ __forceinline__ void inv_B(int tid, float* re, float* im) {
    #pragma unroll
    for (int gg = 0; gg < 2; ++gg) {
        const int g = tid + (gg << 8);
        const int base = ((g >> 4) << 8) | (g & 15);
        float xr[16], xi[16], twr[15], twi[15];
        #pragma unroll
        for (int m = 0; m < 16; ++m) {
            const int p = PHYS(base + (m << 4));
            xr[m] = re[p]; xi[m] = im[p];
        }
        fill_pyr<3>((TWO_PI / 256.0f) * (float)(g & 15), CP8, SP8, twr, twi);
        dit_apply<4>(xr, xi, twr, twi);
        #pragma unroll
        for (int m = 0; m < 16; ++m) {
            const int p = PHYS(base + (m << 4));
            re[p] = xr[m]; im[p] = xi[m];
        }
    }
}

__global__ __launch_bounds__(NT) void conv_fused(const float* __restrict__ u,
                                                 const float* __restrict__ K,
                                                 const float* __restrict__ D,
                                                 float* __restrict__ out) {
    __shared__ float re[LL];
    __shared__ float im[LL];
    const int tid = threadIdx.x;
    const int h = blockIdx.x & (HH - 1);       // same-h blocks 256 apart -> same XCD
    const int pr_ = blockIdx.x >> 8;           // batch pair 0..3

    // ---- Phase K: spectrum of K[h], kept in pass-C register layout ----
    float kr[2][16], ki[2][16];
    {
        const float* Krow = K + (size_t)h * LL;
        float ar[32], ai[32];
        #pragma unroll
        for (int m = 0; m < 32; ++m) {
            ar[m] = Krow[tid + (m << 8)];
            ai[m] = 0.0f;
        }
        fwd_A(ar, ai, tid, re, im);
        __syncthreads();
        fwd_B(tid, re, im);
        __syncthreads();
        const float dh = D[h];
        const float invN = 1.0f / (float)LL;
        #pragma unroll
        for (int gg = 0; gg < 2; ++gg) {
            const int base = (tid + (gg << 8)) << 4;
            float yr[16], yi[16], twr[15], twi[15];
            #pragma unroll
            for (int m = 0; m < 16; ++m) {
                const int p = PHYS(base + m);
                yr[m] = re[p]; yi[m] = im[p];
            }
            fill_pyr_cs<3>(1.0f, 0.0f, CP8, -SP8, twr, twi);
            dif_apply<4>(yr, yi, twr, twi);
            // kw = (Kf + D) / N  — skip connection + IFFT normalization folded in.
            #pragma unroll
            for (int m = 0; m < 16; ++m) {
                kr[gg][m] = (yr[m] + dh) * invN;
                ki[gg][m] = yi[m] * invN;
            }
        }
        __syncthreads();
    }

    // ---- Phase U: z = u0 + i*u1; y0 = Re, y1 = Im of IFFT(FFT(z)*kw) ----
    const size_t off0 = ((size_t)(pr_ * 2) * HH + h) * LL;
    const size_t off1 = off0 + (size_t)HH * LL;
    const float* u0 = u + off0;
    const float* u1 = u + off1;

    float xr[32], xi[32];
    #pragma unroll
    for (int m = 0; m < 32; ++m) {
        xr[m] = u0[tid + (m << 8)];
        xi[m] = u1[tid + (m << 8)];
    }
    fwd_A(xr, xi, tid, re, im);
    __syncthreads();
    fwd_B(tid, re, im);
    __syncthreads();

    // Merged pass C: fwd stages 3..0, pointwise * kw (registers), inv stages 0..3.
    #pragma unroll
    for (int gg = 0; gg < 2; ++gg) {
        const int base = (tid + (gg << 8)) << 4;
        float yr[16], yi[16], twr[15], twi[15];
        #pragma unroll
        for (int m = 0; m < 16; ++m) {
            const int p = PHYS(base + m);
            yr[m] = re[p]; yi[m] = im[p];
        }
        fill_pyr_cs<3>(1.0f, 0.0f, CP8, -SP8, twr, twi);
        dif_apply<4>(yr, yi, twr, twi);
        #pragma unroll
        for (int m = 0; m < 16; ++m) {
            const float a = yr[m], b = yi[m];
            yr[m] = a * kr[gg][m] - b * ki[gg][m];
            yi[m] = a * ki[gg][m] + b * kr[gg][m];
        }
        fill_pyr_cs<3>(1.0f, 0.0f, CP8, SP8, twr, twi);
        dit_apply<4>(yr, yi, twr, twi);
        #pragma unroll
        for (int m = 0; m < 16; ++m) {
            const int p = PHYS(base + m);
            re[p] = yr[m]; im[p] = yi[m];
        }
    }
    __syncthreads();

    inv_B(tid, re, im);
    __syncthreads();

    // Inv pass A' (stages 8..12) + fused epilogue.
    {
        float twr[31], twi[31];
        #pragma unroll
        for (int m = 0; m < 32; ++m) {
            const int p = PHYS(tid + (m << 8));
            xr[m] = re[p]; xi[m] = im[p];
        }
        fill_pyr<4>((TWO_PI / 8192.0f) * (float)tid, CP16, SP16, twr, twi);
        dit_apply<5>(xr, xi, twr, twi);
    }
    float* o0 = out + off0;
    float* o1 = out + off1;
    #pragma unroll
    for (int m = 0; m < 32; ++m) {
        const int n = tid + (m << 8);
        o0[n] = fast_tanh(xr[m]);
        o1[n] = fast_tanh(xi[m]);
    }
}

extern "C" void kernel_launch(void* const* d_in, const int* in_sizes, int n_in,
                              void* d_out, int out_size, void* d_ws, size_t ws_size,
                              hipStream_t stream) {
    const float* u = (const float*)d_in[0];   // (8, 256, 8192)
    const float* K = (const float*)d_in[1];   // (256, 8192)
    const float* D = (const float*)d_in[2];   // (256,)
    float* out = (float*)d_out;               // (8, 256, 8192)

    conv_fused<<<dim3(4 * HH), dim3(NT), 0, stream>>>(u, K, D, out);
}